// Round 15
// baseline (126.570 us; speedup 1.0000x reference)
//
#include <hip/hip_runtime.h>
#include <hip/hip_fp16.h>

#define USER_NUM 100000
#define ITEM_NUM 50000
#define N_NODES  150000
#define NNZ      1200000
#define BATCH    4096
#define HIDDEN   64

#define BUCK_SHIFT 10
#define NBUCK 147        // ceil(150000/1024)
#define BCAP  10240      // fixed bucket capacity (mean 8192, sigma ~90)
#define BINA_CHUNK 4096  // edges per block in pass A (16 per thread)
#define MAXPAIRS 131072  // cap for (target, j-edge) pairs (mean ~65536)

// ---- fp16 pack/unpack (RNE, exact widen) ----
__device__ __forceinline__ unsigned pack2(float a, float b) {
    __half2 h = __floats2half2_rn(a, b);
    return *(unsigned*)&h;
}
__device__ __forceinline__ float4 unpack4(uint2 u) {
    __half2 h0 = *(__half2*)&u.x;
    __half2 h1 = *(__half2*)&u.y;
    float2 f0 = __half22float2(h0);
    float2 f1 = __half22float2(h1);
    return make_float4(f0.x, f0.y, f1.x, f1.y);
}

// emb f32 -> unified packed fp16 table (8 elems / thread); block 0 also
// zeroes cursorB (ordered before binA on the same stream)
__global__ void convert_kernel(const float* __restrict__ ue, const float* __restrict__ ie,
                               uint4* __restrict__ embh, int* __restrict__ cursorB) {
    if (blockIdx.x == 0 && threadIdx.x < NBUCK) cursorB[threadIdx.x] = 0;
    int idx = blockIdx.x * blockDim.x + threadIdx.x;
    const int total8 = N_NODES * HIDDEN / 8;
    if (idx >= total8) return;
    const int usz8 = USER_NUM * HIDDEN / 8;
    const float4* base = (idx < usz8) ? (const float4*)ue + (size_t)idx * 2
                                      : (const float4*)ie + (size_t)(idx - usz8) * 2;
    float4 a = base[0], b = base[1];
    embh[idx] = make_uint4(pack2(a.x, a.y), pack2(a.z, a.w),
                           pack2(b.x, b.y), pack2(b.z, b.w));
}

// pass A: bucket-partition edges, LDS-aggregated; cursorB starts at 0,
// placement = binned[b*BCAP + prior + r]
__global__ void binA_kernel(const int* __restrict__ src, const int* __restrict__ dst,
                            const float* __restrict__ ew,
                            int* __restrict__ cursorB, int2* __restrict__ binned) {
    __shared__ int hist[NBUCK];
    __shared__ int base[NBUCK];
    const int chunk0 = blockIdx.x * BINA_CHUNK;
    for (int i = threadIdx.x; i < NBUCK; i += 256) hist[i] = 0;
    __syncthreads();
    for (int k = 0; k < BINA_CHUNK / 256; ++k) {
        int e = chunk0 + k * 256 + threadIdx.x;
        if (e < NNZ) atomicAdd(&hist[dst[e] >> BUCK_SHIFT], 1);
    }
    __syncthreads();
    for (int i = threadIdx.x; i < NBUCK; i += 256) {
        int c = hist[i];
        base[i] = c ? atomicAdd(&cursorB[i], c) : 0;
        hist[i] = 0;
    }
    __syncthreads();
    for (int k = 0; k < BINA_CHUNK / 256; ++k) {
        int e = chunk0 + k * 256 + threadIdx.x;
        if (e < NNZ) {
            int d = dst[e];
            int b = d >> BUCK_SHIFT;
            int r = atomicAdd(&hist[b], 1);
            binned[(size_t)b * BCAP + base[b] + r] =
                make_int2(src[e] | ((d & 1023) << 18), __float_as_int(ew[e]));
        }
    }
}

// pass B: one block per bucket. Inline global-base scan, LDS per-node
// histogram -> block scan -> coalesced rowp write -> LDS-cursor scatter.
__global__ __launch_bounds__(1024) void binB_kernel(const int2* __restrict__ binned,
                                                    const int* __restrict__ cursorB,
                                                    int* __restrict__ rowp,
                                                    int2* __restrict__ srcw) {
    __shared__ int hist[1 << BUCK_SHIFT];
    __shared__ int sb[256];
    __shared__ int wsum[16];
    const int b = blockIdx.x;
    const int tid = threadIdx.x;
    hist[tid] = 0;
    if (tid < 256) sb[tid] = (tid < NBUCK) ? cursorB[tid] : 0;
    __syncthreads();
    for (int off = 1; off < 256; off <<= 1) {
        int t2 = 0;
        if (tid < 256 && tid >= off) t2 = sb[tid - off];
        __syncthreads();
        if (tid < 256) sb[tid] += t2;
        __syncthreads();
    }
    const int bucketBase = (b == 0) ? 0 : sb[b - 1];
    const int cnt = cursorB[b];
    const size_t lo = (size_t)b * BCAP;
    for (int i = tid; i < cnt; i += 1024)
        atomicAdd(&hist[(unsigned)binned[lo + i].x >> 18], 1);
    __syncthreads();
    const int v = hist[tid];
    const int lane = tid & 63, w = tid >> 6;
    int x = v;
    for (int off = 1; off < 64; off <<= 1) {
        int y = __shfl_up(x, off, 64);
        if (lane >= off) x += y;
    }
    if (lane == 63) wsum[w] = x;
    __syncthreads();
    if (tid < 16) {
        int orig = wsum[tid];
        int s = orig;
        for (int off = 1; off < 16; off <<= 1) {
            int y = __shfl_up(s, off, 64);
            if (tid >= off) s += y;
        }
        wsum[tid] = s - orig;
    }
    __syncthreads();
    const int excl = bucketBase + (x - v) + wsum[w];
    const int nodeBase = b << BUCK_SHIFT;
    if (nodeBase + tid < N_NODES) rowp[nodeBase + tid] = excl;
    if (b == 0 && tid == 0) rowp[N_NODES] = NNZ;
    hist[tid] = excl;
    __syncthreads();
    for (int i = tid; i < cnt; i += 1024) {
        int2 p = binned[lo + i];
        int dl = (unsigned)p.x >> 18;
        int pos = atomicAdd(&hist[dl], 1);
        srcw[pos] = make_int2(p.x & 0x3FFFF, p.y);
    }
}

// ---- gather core v4: 16-lane group per node, fp16 rows (128B = uint2/lane),
// coalesced edge load + shfl redistribute, 8 rows in flight, f32 accum ----
__device__ __forceinline__ float4 gather_node_v4(int start, int end, int gl,
                                                 const int2* __restrict__ srcw,
                                                 const uint2* __restrict__ rows) {
    float4 acc = make_float4(0.f, 0.f, 0.f, 0.f);
    for (int base = start; base < end; base += 16) {
        int2 e = make_int2(0, 0);
        if (base + gl < end) e = srcw[base + gl];   // one coalesced 128B load per group
        int m = end - base; if (m > 16) m = 16;
        for (int j0 = 0; j0 < m; j0 += 8) {
            const uint2* bp[8];
            float w[8];
            #pragma unroll
            for (int k = 0; k < 8; ++k) {
                int idx = j0 + k;
                int ss = __shfl(e.x, idx, 16);
                float ww = __int_as_float(__shfl(e.y, idx, 16));
                bool valid = idx < m;
                ss = valid ? ss : 0;
                w[k] = valid ? ww : 0.f;
                bp[k] = rows + (size_t)ss * 16 + gl;
            }
            uint2 v[8];
            #pragma unroll
            for (int k = 0; k < 8; ++k) v[k] = *bp[k];
            #pragma unroll
            for (int k = 0; k < 8; ++k) {
                float4 f = unpack4(v[k]);
                acc.x = fmaf(w[k], f.x, acc.x);
                acc.y = fmaf(w[k], f.y, acc.y);
                acc.z = fmaf(w[k], f.z, acc.z);
                acc.w = fmaf(w[k], f.w, acc.w);
            }
        }
    }
    return acc;
}

// layer 1: all nodes; gathers fp16 emb rows, writes fp16 c1h
__global__ void spmm_gather_kernel(const int* __restrict__ rowp,
                                   const int2* __restrict__ srcw,
                                   const uint2* __restrict__ embh,
                                   uint2* __restrict__ c1h) {
    int wid = (blockIdx.x * blockDim.x + threadIdx.x) >> 6;
    int lane = threadIdx.x & 63;
    int grp = lane >> 4, gl = lane & 15;
    int n = wid * 4 + grp;
    bool act = (n < N_NODES);
    int start = 0, end = 0;
    if (act) { start = rowp[n]; end = rowp[n + 1]; }
    float4 acc = gather_node_v4(start, end, gl, srcw, embh);
    if (act) c1h[(size_t)n * 16 + gl] = make_uint2(pack2(acc.x, acc.y), pack2(acc.z, acc.w));
}

// single-block: compute per-target degrees from rowp and exclusive-scan ->
// toff; toff[8192] = total pairs
__global__ __launch_bounds__(1024) void pair_scan_kernel(const int* __restrict__ user,
                                                         const int* __restrict__ item,
                                                         const int* __restrict__ rowp,
                                                         int* __restrict__ toff) {
    __shared__ int wsum[16];
    const int tid = threadIdx.x;
    int v[8];
    int s = 0;
    #pragma unroll
    for (int k = 0; k < 8; ++k) {
        int t = tid * 8 + k;
        int n = (t < BATCH) ? user[t] : USER_NUM + item[t - BATCH];
        v[k] = rowp[n + 1] - rowp[n];
        s += v[k];
    }
    const int lane = tid & 63, w = tid >> 6;
    int x = s;
    for (int off = 1; off < 64; off <<= 1) {
        int y = __shfl_up(x, off, 64);
        if (lane >= off) x += y;
    }
    if (lane == 63) wsum[w] = x;
    __syncthreads();
    if (tid < 16) {
        int orig = wsum[tid];
        int ss = orig;
        for (int off = 1; off < 16; off <<= 1) {
            int y = __shfl_up(ss, off, 64);
            if (tid >= off) ss += y;
        }
        wsum[tid] = ss - orig;
    }
    __syncthreads();
    int excl = (x - s) + wsum[w];
    #pragma unroll
    for (int k = 0; k < 8; ++k) { toff[tid * 8 + k] = excl; excl += v[k]; }
    if (tid == 1023) toff[2 * BATCH] = excl;   // npairs
}

// expand: one 16-lane group per target writes its packed pairs coalesced
__global__ void expand_kernel(const int* __restrict__ user, const int* __restrict__ item,
                              const int* __restrict__ rowp, const int2* __restrict__ srcw,
                              const int* __restrict__ toff, int2* __restrict__ pairs) {
    int gid = (blockIdx.x * blockDim.x + threadIdx.x) >> 4;
    int gl = threadIdx.x & 15;
    if (gid >= 2 * BATCH) return;
    int t = gid;
    int n = (t < BATCH) ? user[t] : USER_NUM + item[t - BATCH];
    int s1 = rowp[n];
    int d = rowp[n + 1] - s1;
    int base = toff[t];
    for (int i = gl; i < d; i += 16) {
        int idx = base + i;
        if (idx < MAXPAIRS) {
            int2 e = srcw[s1 + i];
            pairs[idx] = make_int2(e.x | (t << 18), e.y);
        }
    }
}

// pair gather: grid-stride 16-lane groups over pairs.
// partial[p] = wj * (c1h[sj] + sum_k wk*c1h[sk])
__global__ void pair_gather_kernel(const int2* __restrict__ pairs, const int* __restrict__ toff,
                                   const int* __restrict__ rowp, const int2* __restrict__ srcw,
                                   const uint2* __restrict__ c1h, float* __restrict__ partial) {
    int gid = (blockIdx.x * blockDim.x + threadIdx.x) >> 4;
    int gl = threadIdx.x & 15;
    int ngroups = (gridDim.x * blockDim.x) >> 4;
    int npairs = toff[2 * BATCH];
    if (npairs > MAXPAIRS) npairs = MAXPAIRS;
    for (int p = gid; p < npairs; p += ngroups) {
        int2 pe = pairs[p];
        int sj = pe.x & 0x3FFFF;
        float wj = __int_as_float(pe.y);
        float4 f1 = unpack4(c1h[(size_t)sj * 16 + gl]);
        float4 inner = gather_node_v4(rowp[sj], rowp[sj + 1], gl, srcw, c1h);
        float4 acc = make_float4(wj * (f1.x + inner.x), wj * (f1.y + inner.y),
                                 wj * (f1.z + inner.z), wj * (f1.w + inner.w));
        *(float4*)(partial + (size_t)p * HIDDEN + gl * 4) = acc;
    }
}

// reduce: one 16-lane group per target: sums[t] = emb[n] + c1h[n] + sum partials
__global__ void reduce_kernel(const int* __restrict__ user, const int* __restrict__ item,
                              const int* __restrict__ toff, const float* __restrict__ partial,
                              const uint2* __restrict__ c1h,
                              const float* __restrict__ user_emb, const float* __restrict__ item_emb,
                              float* __restrict__ sums) {
    int gid = (blockIdx.x * blockDim.x + threadIdx.x) >> 4;
    int gl = threadIdx.x & 15;
    if (gid >= 2 * BATCH) return;
    int t = gid;
    int n = (t < BATCH) ? user[t] : USER_NUM + item[t - BATCH];
    const float* ebase = (n < USER_NUM) ? user_emb + (size_t)n * HIDDEN
                                        : item_emb + (size_t)(n - USER_NUM) * HIDDEN;
    float4 ev = *(const float4*)(ebase + gl * 4);
    float4 cv = unpack4(c1h[(size_t)n * 16 + gl]);
    float4 acc = make_float4(ev.x + cv.x, ev.y + cv.y, ev.z + cv.z, ev.w + cv.w);
    int p0 = toff[t], p1 = toff[t + 1];
    if (p1 > MAXPAIRS) p1 = MAXPAIRS;
    for (int p = p0; p < p1; ++p) {
        float4 pv = *(const float4*)(partial + (size_t)p * HIDDEN + gl * 4);
        acc.x += pv.x; acc.y += pv.y; acc.z += pv.z; acc.w += pv.w;
    }
    *(float4*)(sums + (size_t)t * HIDDEN + gl * 4) = acc;
}

// one 64-lane wave per batch element
__global__ void dot_kernel(const float* __restrict__ sums, float* __restrict__ out) {
    int b = blockIdx.x * (blockDim.x >> 6) + (threadIdx.x >> 6);
    int lane = threadIdx.x & 63;
    if (b >= BATCH) return;
    float su = sums[(size_t)b * HIDDEN + lane];
    float si = sums[(size_t)(BATCH + b) * HIDDEN + lane];
    float p = su * si;
    for (int off = 32; off > 0; off >>= 1) p += __shfl_down(p, off, 64);
    if (lane == 0) {
        float g = 0.0625f * p;  // 0.25 per side (all alphas equal)
        out[b] = 1.0f / (1.0f + expf(-g));
    }
}

extern "C" void kernel_launch(void* const* d_in, const int* in_sizes, int n_in,
                              void* d_out, int out_size, void* d_ws, size_t ws_size,
                              hipStream_t stream) {
    const int*   user     = (const int*)d_in[0];
    const int*   item     = (const int*)d_in[1];
    const int*   src      = (const int*)d_in[2];
    const int*   dst      = (const int*)d_in[3];
    const float* ew       = (const float*)d_in[4];
    const float* user_emb = (const float*)d_in[5];
    const float* item_emb = (const float*)d_in[6];
    float* out = (float*)d_out;

    float* sums    = (float*)d_ws;                               // [8192][64]
    float* partial = sums + (size_t)2 * BATCH * HIDDEN;          // [MAXPAIRS][64]
    uint2* embh    = (uint2*)(partial + (size_t)MAXPAIRS * HIDDEN); // [N_NODES][16]
    uint2* c1h     = embh + (size_t)N_NODES * 16;                // [N_NODES][16]
    int2*  srcw    = (int2*)(c1h + (size_t)N_NODES * 16);        // NNZ + pad
    int2*  binned  = srcw + NNZ + 16;                            // NBUCK*BCAP
    int2*  pairs   = binned + (size_t)NBUCK * BCAP;              // MAXPAIRS
    int*   rowp    = (int*)(pairs + MAXPAIRS);                   // N_NODES+1
    int*   cursorB = rowp + N_NODES + 1;                         // NBUCK
    int*   toff    = cursorB + NBUCK;                            // 2*BATCH+1

    // ---- emb -> fp16 table; block 0 zeroes cursorB (no blit memset) ----
    const int total8 = N_NODES * HIDDEN / 8;
    convert_kernel<<<(total8 + 255) / 256, 256, 0, stream>>>(user_emb, item_emb, (uint4*)embh, cursorB);

    // ---- CSR build (by dst): bucket partition + fused hist/scan/scatter ----
    binA_kernel<<<(NNZ + BINA_CHUNK - 1) / BINA_CHUNK, 256, 0, stream>>>(src, dst, ew, cursorB, binned);
    binB_kernel<<<NBUCK, 1024, 0, stream>>>(binned, cursorB, rowp, srcw);

    // ---- pair expansion for 2-hop (tdeg fused into scan) ----
    pair_scan_kernel<<<1, 1024, 0, stream>>>(user, item, rowp, toff);
    expand_kernel<<<(2 * BATCH * 16 + 255) / 256, 256, 0, stream>>>(user, item, rowp, srcw, toff, pairs);

    // ---- layer 1: full (16 nodes per 256-thread block) ----
    const int nodesPerBlock = 16;
    const int nGatherBlocks = (N_NODES + nodesPerBlock - 1) / nodesPerBlock;
    spmm_gather_kernel<<<nGatherBlocks, 256, 0, stream>>>(rowp, srcw, embh, c1h);

    // ---- pair-parallel 2-hop gather + per-target reduce ----
    pair_gather_kernel<<<1024, 256, 0, stream>>>(pairs, toff, rowp, srcw, c1h, partial);
    reduce_kernel<<<(2 * BATCH * 16 + 255) / 256, 256, 0, stream>>>(
        user, item, toff, partial, c1h, user_emb, item_emb, sums);

    dot_kernel<<<(BATCH * 64 + 255) / 256, 256, 0, stream>>>(sums, out);
}

// Round 16
// 103.761 us; speedup vs baseline: 1.2198x; 1.2198x over previous
//
#include <hip/hip_runtime.h>
#include <hip/hip_fp16.h>

#define USER_NUM 100000
#define ITEM_NUM 50000
#define N_NODES  150000
#define NNZ      1200000
#define BATCH    4096
#define HIDDEN   64

#define BUCK_SHIFT 10
#define NBUCK 147        // ceil(150000/1024)
#define BCAP  10240      // fixed bucket capacity (mean 8192, sigma ~90)
#define BINA_CHUNK 4096  // edges per block in pass A (16 per thread)
#define NBINA ((NNZ + BINA_CHUNK - 1) / BINA_CHUNK)   // 293
#define TOTAL8 (N_NODES * HIDDEN / 8)                  // 1.2M
#define CONVB ((TOTAL8 + 255) / 256)                   // 4688

// ---- fp16 pack/unpack (RNE, exact widen) ----
__device__ __forceinline__ unsigned pack2(float a, float b) {
    __half2 h = __floats2half2_rn(a, b);
    return *(unsigned*)&h;
}
__device__ __forceinline__ float4 unpack4(uint2 u) {
    __half2 h0 = *(__half2*)&u.x;
    __half2 h1 = *(__half2*)&u.y;
    float2 f0 = __half22float2(h0);
    float2 f1 = __half22float2(h1);
    return make_float4(f0.x, f0.y, f1.x, f1.y);
}

__global__ void init_kernel(int* __restrict__ cursorB) {
    if (threadIdx.x < NBUCK) cursorB[threadIdx.x] = 0;
}

// merged: blocks [0,NBINA) bucket-partition edges (binA); blocks [NBINA, ...)
// convert emb f32 -> packed fp16 table. Independent work, co-scheduled.
__global__ void convbinA_kernel(const int* __restrict__ src, const int* __restrict__ dst,
                                const float* __restrict__ ew,
                                int* __restrict__ cursorB, int2* __restrict__ binned,
                                const float* __restrict__ ue, const float* __restrict__ ie,
                                uint4* __restrict__ embh) {
    if (blockIdx.x >= NBINA) {
        int idx = (blockIdx.x - NBINA) * blockDim.x + threadIdx.x;
        if (idx >= TOTAL8) return;
        const int usz8 = USER_NUM * HIDDEN / 8;
        const float4* base = (idx < usz8) ? (const float4*)ue + (size_t)idx * 2
                                          : (const float4*)ie + (size_t)(idx - usz8) * 2;
        float4 a = base[0], b = base[1];
        embh[idx] = make_uint4(pack2(a.x, a.y), pack2(a.z, a.w),
                               pack2(b.x, b.y), pack2(b.z, b.w));
        return;
    }
    __shared__ int hist[NBUCK];
    __shared__ int base[NBUCK];
    const int chunk0 = blockIdx.x * BINA_CHUNK;
    for (int i = threadIdx.x; i < NBUCK; i += 256) hist[i] = 0;
    __syncthreads();
    for (int k = 0; k < BINA_CHUNK / 256; ++k) {
        int e = chunk0 + k * 256 + threadIdx.x;
        if (e < NNZ) atomicAdd(&hist[dst[e] >> BUCK_SHIFT], 1);
    }
    __syncthreads();
    for (int i = threadIdx.x; i < NBUCK; i += 256) {
        int c = hist[i];
        base[i] = c ? atomicAdd(&cursorB[i], c) : 0;
        hist[i] = 0;
    }
    __syncthreads();
    for (int k = 0; k < BINA_CHUNK / 256; ++k) {
        int e = chunk0 + k * 256 + threadIdx.x;
        if (e < NNZ) {
            int d = dst[e];
            int b = d >> BUCK_SHIFT;
            int r = atomicAdd(&hist[b], 1);
            binned[(size_t)b * BCAP + base[b] + r] =
                make_int2(src[e] | ((d & 1023) << 18), __float_as_int(ew[e]));
        }
    }
}

// pass B: one block per bucket. Inline global-base scan, LDS per-node
// histogram -> block scan -> coalesced rowp write -> LDS-cursor scatter.
__global__ __launch_bounds__(1024) void binB_kernel(const int2* __restrict__ binned,
                                                    const int* __restrict__ cursorB,
                                                    int* __restrict__ rowp,
                                                    int2* __restrict__ srcw) {
    __shared__ int hist[1 << BUCK_SHIFT];
    __shared__ int sb[256];
    __shared__ int wsum[16];
    const int b = blockIdx.x;
    const int tid = threadIdx.x;
    hist[tid] = 0;
    if (tid < 256) sb[tid] = (tid < NBUCK) ? cursorB[tid] : 0;
    __syncthreads();
    for (int off = 1; off < 256; off <<= 1) {
        int t2 = 0;
        if (tid < 256 && tid >= off) t2 = sb[tid - off];
        __syncthreads();
        if (tid < 256) sb[tid] += t2;
        __syncthreads();
    }
    const int bucketBase = (b == 0) ? 0 : sb[b - 1];
    const int cnt = cursorB[b];
    const size_t lo = (size_t)b * BCAP;
    for (int i = tid; i < cnt; i += 1024)
        atomicAdd(&hist[(unsigned)binned[lo + i].x >> 18], 1);
    __syncthreads();
    const int v = hist[tid];
    const int lane = tid & 63, w = tid >> 6;
    int x = v;
    for (int off = 1; off < 64; off <<= 1) {
        int y = __shfl_up(x, off, 64);
        if (lane >= off) x += y;
    }
    if (lane == 63) wsum[w] = x;
    __syncthreads();
    if (tid < 16) {
        int orig = wsum[tid];
        int s = orig;
        for (int off = 1; off < 16; off <<= 1) {
            int y = __shfl_up(s, off, 64);
            if (tid >= off) s += y;
        }
        wsum[tid] = s - orig;
    }
    __syncthreads();
    const int excl = bucketBase + (x - v) + wsum[w];
    const int nodeBase = b << BUCK_SHIFT;
    if (nodeBase + tid < N_NODES) rowp[nodeBase + tid] = excl;
    if (b == 0 && tid == 0) rowp[N_NODES] = NNZ;
    hist[tid] = excl;
    __syncthreads();
    for (int i = tid; i < cnt; i += 1024) {
        int2 p = binned[lo + i];
        int dl = (unsigned)p.x >> 18;
        int pos = atomicAdd(&hist[dl], 1);
        srcw[pos] = make_int2(p.x & 0x3FFFF, p.y);
    }
}

// ---- gather core v4: 16-lane group per node, fp16 rows (128B = uint2/lane),
// coalesced edge load + shfl redistribute, 8 rows in flight, f32 accum.
// Loop bounds must be group-uniform. ----
__device__ __forceinline__ float4 gather_node_v4(int start, int end, int gl,
                                                 const int2* __restrict__ srcw,
                                                 const uint2* __restrict__ rows) {
    float4 acc = make_float4(0.f, 0.f, 0.f, 0.f);
    for (int base = start; base < end; base += 16) {
        int2 e = make_int2(0, 0);
        if (base + gl < end) e = srcw[base + gl];   // one coalesced 128B load per group
        int m = end - base; if (m > 16) m = 16;
        for (int j0 = 0; j0 < m; j0 += 8) {
            const uint2* bp[8];
            float w[8];
            #pragma unroll
            for (int k = 0; k < 8; ++k) {
                int idx = j0 + k;
                int ss = __shfl(e.x, idx, 16);
                float ww = __int_as_float(__shfl(e.y, idx, 16));
                bool valid = idx < m;
                ss = valid ? ss : 0;
                w[k] = valid ? ww : 0.f;
                bp[k] = rows + (size_t)ss * 16 + gl;
            }
            uint2 v[8];
            #pragma unroll
            for (int k = 0; k < 8; ++k) v[k] = *bp[k];
            #pragma unroll
            for (int k = 0; k < 8; ++k) {
                float4 f = unpack4(v[k]);
                acc.x = fmaf(w[k], f.x, acc.x);
                acc.y = fmaf(w[k], f.y, acc.y);
                acc.z = fmaf(w[k], f.z, acc.z);
                acc.w = fmaf(w[k], f.w, acc.w);
            }
        }
    }
    return acc;
}

// layer 1: all nodes; gathers fp16 emb rows, writes fp16 c1h
__global__ void spmm_gather_kernel(const int* __restrict__ rowp,
                                   const int2* __restrict__ srcw,
                                   const uint2* __restrict__ embh,
                                   uint2* __restrict__ c1h) {
    int wid = (blockIdx.x * blockDim.x + threadIdx.x) >> 6;
    int lane = threadIdx.x & 63;
    int grp = lane >> 4, gl = lane & 15;
    int n = wid * 4 + grp;
    bool act = (n < N_NODES);
    int start = 0, end = 0;
    if (act) { start = rowp[n]; end = rowp[n + 1]; }
    float4 acc = gather_node_v4(start, end, gl, srcw, embh);
    if (act) c1h[(size_t)n * 16 + gl] = make_uint2(pack2(acc.x, acc.y), pack2(acc.z, acc.w));
}

// fused 2-hop: ONE 64-LANE WAVE per target t. The 4 groups take j-edges
// round-robin (each group: c1h[sj] + 8-in-flight inner gather over sj's
// in-edges); cross-group shfl_xor reduce; group 0 adds emb + c1h[n] and
// writes sums[t]. 8192 waves -> full occupancy, no intermediates.
__global__ void twohop_kernel(const int* __restrict__ user, const int* __restrict__ item,
                              const int* __restrict__ rowp, const int2* __restrict__ srcw,
                              const uint2* __restrict__ c1h,
                              const float* __restrict__ user_emb,
                              const float* __restrict__ item_emb,
                              float* __restrict__ sums) {
    int wid = (blockIdx.x * blockDim.x + threadIdx.x) >> 6;
    int lane = threadIdx.x & 63;
    int grp = lane >> 4, gl = lane & 15;
    if (wid >= 2 * BATCH) return;
    int t = wid;
    int n = (t < BATCH) ? user[t] : USER_NUM + item[t - BATCH];
    int s1 = rowp[n], e1 = rowp[n + 1];
    float4 acc = make_float4(0.f, 0.f, 0.f, 0.f);
    for (int jb = s1 + grp; jb < e1; jb += 4) {
        int2 ej = srcw[jb];                       // group-uniform 8B broadcast
        int sj = ej.x;
        float wj = __int_as_float(ej.y);
        float4 f1 = unpack4(c1h[(size_t)sj * 16 + gl]);
        float4 inner = gather_node_v4(rowp[sj], rowp[sj + 1], gl, srcw, c1h);
        acc.x = fmaf(wj, f1.x + inner.x, acc.x);
        acc.y = fmaf(wj, f1.y + inner.y, acc.y);
        acc.z = fmaf(wj, f1.z + inner.z, acc.z);
        acc.w = fmaf(wj, f1.w + inner.w, acc.w);
    }
    for (int m = 16; m < 64; m <<= 1) {
        acc.x += __shfl_xor(acc.x, m, 64);
        acc.y += __shfl_xor(acc.y, m, 64);
        acc.z += __shfl_xor(acc.z, m, 64);
        acc.w += __shfl_xor(acc.w, m, 64);
    }
    if (grp == 0) {
        const float* ebase = (n < USER_NUM) ? user_emb + (size_t)n * HIDDEN
                                            : item_emb + (size_t)(n - USER_NUM) * HIDDEN;
        float4 ev = *(const float4*)(ebase + gl * 4);
        float4 cv = unpack4(c1h[(size_t)n * 16 + gl]);
        float4 o = make_float4(ev.x + cv.x + acc.x, ev.y + cv.y + acc.y,
                               ev.z + cv.z + acc.z, ev.w + cv.w + acc.w);
        *(float4*)(sums + (size_t)t * HIDDEN + gl * 4) = o;
    }
}

// one 64-lane wave per batch element
__global__ void dot_kernel(const float* __restrict__ sums, float* __restrict__ out) {
    int b = blockIdx.x * (blockDim.x >> 6) + (threadIdx.x >> 6);
    int lane = threadIdx.x & 63;
    if (b >= BATCH) return;
    float su = sums[(size_t)b * HIDDEN + lane];
    float si = sums[(size_t)(BATCH + b) * HIDDEN + lane];
    float p = su * si;
    for (int off = 32; off > 0; off >>= 1) p += __shfl_down(p, off, 64);
    if (lane == 0) {
        float g = 0.0625f * p;  // 0.25 per side (all alphas equal)
        out[b] = 1.0f / (1.0f + expf(-g));
    }
}

extern "C" void kernel_launch(void* const* d_in, const int* in_sizes, int n_in,
                              void* d_out, int out_size, void* d_ws, size_t ws_size,
                              hipStream_t stream) {
    const int*   user     = (const int*)d_in[0];
    const int*   item     = (const int*)d_in[1];
    const int*   src      = (const int*)d_in[2];
    const int*   dst      = (const int*)d_in[3];
    const float* ew       = (const float*)d_in[4];
    const float* user_emb = (const float*)d_in[5];
    const float* item_emb = (const float*)d_in[6];
    float* out = (float*)d_out;

    float* sums    = (float*)d_ws;                               // [8192][64]
    uint2* embh    = (uint2*)(sums + (size_t)2 * BATCH * HIDDEN); // [N_NODES][16]
    uint2* c1h     = embh + (size_t)N_NODES * 16;                // [N_NODES][16]
    int2*  srcw    = (int2*)(c1h + (size_t)N_NODES * 16);        // NNZ + pad
    int2*  binned  = srcw + NNZ + 16;                            // NBUCK*BCAP
    int*   rowp    = (int*)(binned + (size_t)NBUCK * BCAP);      // N_NODES+1
    int*   cursorB = rowp + N_NODES + 1;                         // NBUCK

    // ---- zero bucket cursors ----
    init_kernel<<<1, 256, 0, stream>>>(cursorB);

    // ---- fused: bucket partition (293 blocks) + emb->fp16 (4688 blocks) ----
    convbinA_kernel<<<NBINA + CONVB, 256, 0, stream>>>(
        src, dst, ew, cursorB, binned, user_emb, item_emb, (uint4*)embh);

    // ---- bucket-local CSR finalize ----
    binB_kernel<<<NBUCK, 1024, 0, stream>>>(binned, cursorB, rowp, srcw);

    // ---- layer 1: full (16 nodes per 256-thread block) ----
    const int nodesPerBlock = 16;
    const int nGatherBlocks = (N_NODES + nodesPerBlock - 1) / nodesPerBlock;
    spmm_gather_kernel<<<nGatherBlocks, 256, 0, stream>>>(rowp, srcw, embh, c1h);

    // ---- fused 2-hop: one wave per target ----
    twohop_kernel<<<(2 * BATCH * 64) / 256, 256, 0, stream>>>(
        user, item, rowp, srcw, c1h, user_emb, item_emb, sums);

    dot_kernel<<<(BATCH * 64 + 255) / 256, 256, 0, stream>>>(sums, out);
}

// Round 17
// 102.479 us; speedup vs baseline: 1.2351x; 1.0125x over previous
//
#include <hip/hip_runtime.h>
#include <hip/hip_fp16.h>

#define USER_NUM 100000
#define ITEM_NUM 50000
#define N_NODES  150000
#define NNZ      1200000
#define BATCH    4096
#define HIDDEN   64

#define BUCK_SHIFT 10
#define NBUCK 147        // ceil(150000/1024)
#define BCAP  10240      // fixed bucket capacity (mean 8192, sigma ~90)
#define BINA_CHUNK 4096  // edges per block (16 per thread)
#define NBINA ((NNZ + BINA_CHUNK - 1) / BINA_CHUNK)   // 293
#define TOTAL8 (N_NODES * HIDDEN / 8)                  // 1.2M
#define CONVB ((TOTAL8 + 255) / 256)                   // 4688

// ---- fp16 pack/unpack (RNE, exact widen) ----
__device__ __forceinline__ unsigned pack2(float a, float b) {
    __half2 h = __floats2half2_rn(a, b);
    return *(unsigned*)&h;
}
__device__ __forceinline__ float4 unpack4(uint2 u) {
    __half2 h0 = *(__half2*)&u.x;
    __half2 h1 = *(__half2*)&u.y;
    float2 f0 = __half22float2(h0);
    float2 f1 = __half22float2(h1);
    return make_float4(f0.x, f0.y, f1.x, f1.y);
}

// pass 1 (fused): blocks [0,NBINA) = per-block bucket histogram -> H;
// blocks [NBINA,...) = emb f32 -> packed fp16 table. No atomic waits.
__global__ void convcount_kernel(const int* __restrict__ dst,
                                 int* __restrict__ H,
                                 const float* __restrict__ ue, const float* __restrict__ ie,
                                 uint4* __restrict__ embh) {
    if (blockIdx.x >= NBINA) {
        int idx = (blockIdx.x - NBINA) * blockDim.x + threadIdx.x;
        if (idx >= TOTAL8) return;
        const int usz8 = USER_NUM * HIDDEN / 8;
        const float4* base = (idx < usz8) ? (const float4*)ue + (size_t)idx * 2
                                          : (const float4*)ie + (size_t)(idx - usz8) * 2;
        float4 a = base[0], b = base[1];
        embh[idx] = make_uint4(pack2(a.x, a.y), pack2(a.z, a.w),
                               pack2(b.x, b.y), pack2(b.z, b.w));
        return;
    }
    __shared__ int hist[NBUCK];
    const int chunk0 = blockIdx.x * BINA_CHUNK;
    for (int i = threadIdx.x; i < NBUCK; i += 256) hist[i] = 0;
    __syncthreads();
    for (int k = 0; k < BINA_CHUNK / 256; ++k) {
        int e = chunk0 + k * 256 + threadIdx.x;
        if (e < NNZ) atomicAdd(&hist[dst[e] >> BUCK_SHIFT], 1);
    }
    __syncthreads();
    for (int i = threadIdx.x; i < NBUCK; i += 256) H[blockIdx.x * NBUCK + i] = hist[i];
}

// pass 2: one block per bucket; exclusive scan of the 293 block counts,
// written back in place; bucket total -> cursorB[b]
__global__ void bin_scan_kernel(int* __restrict__ H, int* __restrict__ cursorB) {
    __shared__ int lds[256];
    __shared__ int carry;
    const int b = blockIdx.x;
    if (threadIdx.x == 0) carry = 0;
    __syncthreads();
    for (int t0 = 0; t0 < NBINA; t0 += 256) {
        int j = t0 + threadIdx.x;
        int v = (j < NBINA) ? H[j * NBUCK + b] : 0;
        lds[threadIdx.x] = v;
        __syncthreads();
        for (int off = 1; off < 256; off <<= 1) {
            int t = (threadIdx.x >= off) ? lds[threadIdx.x - off] : 0;
            __syncthreads();
            lds[threadIdx.x] += t;
            __syncthreads();
        }
        int excl = lds[threadIdx.x] - v + carry;
        if (j < NBINA) H[j * NBUCK + b] = excl;
        __syncthreads();
        if (threadIdx.x == 255) carry += lds[255];
        __syncthreads();
    }
    if (threadIdx.x == 0) cursorB[b] = carry;
}

// pass 3: deterministic placement; LDS-only rank atomics, base from H
__global__ void place_kernel(const int* __restrict__ src, const int* __restrict__ dst,
                             const float* __restrict__ ew,
                             const int* __restrict__ H, int2* __restrict__ binned) {
    __shared__ int rank[NBUCK];
    __shared__ int base[NBUCK];
    const int chunk0 = blockIdx.x * BINA_CHUNK;
    for (int i = threadIdx.x; i < NBUCK; i += 256) {
        base[i] = H[blockIdx.x * NBUCK + i];
        rank[i] = 0;
    }
    __syncthreads();
    for (int k = 0; k < BINA_CHUNK / 256; ++k) {
        int e = chunk0 + k * 256 + threadIdx.x;
        if (e < NNZ) {
            int d = dst[e];
            int b = d >> BUCK_SHIFT;
            int r = atomicAdd(&rank[b], 1);
            binned[(size_t)b * BCAP + base[b] + r] =
                make_int2(src[e] | ((d & 1023) << 18), __float_as_int(ew[e]));
        }
    }
}

// pass B: one block per bucket. Inline global-base scan, LDS per-node
// histogram -> block scan -> coalesced rowp write -> LDS-cursor scatter.
__global__ __launch_bounds__(1024) void binB_kernel(const int2* __restrict__ binned,
                                                    const int* __restrict__ cursorB,
                                                    int* __restrict__ rowp,
                                                    int2* __restrict__ srcw) {
    __shared__ int hist[1 << BUCK_SHIFT];
    __shared__ int sb[256];
    __shared__ int wsum[16];
    const int b = blockIdx.x;
    const int tid = threadIdx.x;
    hist[tid] = 0;
    if (tid < 256) sb[tid] = (tid < NBUCK) ? cursorB[tid] : 0;
    __syncthreads();
    for (int off = 1; off < 256; off <<= 1) {
        int t2 = 0;
        if (tid < 256 && tid >= off) t2 = sb[tid - off];
        __syncthreads();
        if (tid < 256) sb[tid] += t2;
        __syncthreads();
    }
    const int bucketBase = (b == 0) ? 0 : sb[b - 1];
    const int cnt = cursorB[b];
    const size_t lo = (size_t)b * BCAP;
    for (int i = tid; i < cnt; i += 1024)
        atomicAdd(&hist[(unsigned)binned[lo + i].x >> 18], 1);
    __syncthreads();
    const int v = hist[tid];
    const int lane = tid & 63, w = tid >> 6;
    int x = v;
    for (int off = 1; off < 64; off <<= 1) {
        int y = __shfl_up(x, off, 64);
        if (lane >= off) x += y;
    }
    if (lane == 63) wsum[w] = x;
    __syncthreads();
    if (tid < 16) {
        int orig = wsum[tid];
        int s = orig;
        for (int off = 1; off < 16; off <<= 1) {
            int y = __shfl_up(s, off, 64);
            if (tid >= off) s += y;
        }
        wsum[tid] = s - orig;
    }
    __syncthreads();
    const int excl = bucketBase + (x - v) + wsum[w];
    const int nodeBase = b << BUCK_SHIFT;
    if (nodeBase + tid < N_NODES) rowp[nodeBase + tid] = excl;
    if (b == 0 && tid == 0) rowp[N_NODES] = NNZ;
    hist[tid] = excl;
    __syncthreads();
    for (int i = tid; i < cnt; i += 1024) {
        int2 p = binned[lo + i];
        int dl = (unsigned)p.x >> 18;
        int pos = atomicAdd(&hist[dl], 1);
        srcw[pos] = make_int2(p.x & 0x3FFFF, p.y);
    }
}

// ---- gather core v4: 16-lane group per node, fp16 rows (128B = uint2/lane),
// coalesced edge load + shfl redistribute, 8 rows in flight, f32 accum ----
__device__ __forceinline__ float4 gather_node_v4(int start, int end, int gl,
                                                 const int2* __restrict__ srcw,
                                                 const uint2* __restrict__ rows) {
    float4 acc = make_float4(0.f, 0.f, 0.f, 0.f);
    for (int base = start; base < end; base += 16) {
        int2 e = make_int2(0, 0);
        if (base + gl < end) e = srcw[base + gl];   // one coalesced 128B load per group
        int m = end - base; if (m > 16) m = 16;
        for (int j0 = 0; j0 < m; j0 += 8) {
            const uint2* bp[8];
            float w[8];
            #pragma unroll
            for (int k = 0; k < 8; ++k) {
                int idx = j0 + k;
                int ss = __shfl(e.x, idx, 16);
                float ww = __int_as_float(__shfl(e.y, idx, 16));
                bool valid = idx < m;
                ss = valid ? ss : 0;
                w[k] = valid ? ww : 0.f;
                bp[k] = rows + (size_t)ss * 16 + gl;
            }
            uint2 v[8];
            #pragma unroll
            for (int k = 0; k < 8; ++k) v[k] = *bp[k];
            #pragma unroll
            for (int k = 0; k < 8; ++k) {
                float4 f = unpack4(v[k]);
                acc.x = fmaf(w[k], f.x, acc.x);
                acc.y = fmaf(w[k], f.y, acc.y);
                acc.z = fmaf(w[k], f.z, acc.z);
                acc.w = fmaf(w[k], f.w, acc.w);
            }
        }
    }
    return acc;
}

// layer 1: all nodes; gathers fp16 emb rows, writes fp16 c1h
__global__ void spmm_gather_kernel(const int* __restrict__ rowp,
                                   const int2* __restrict__ srcw,
                                   const uint2* __restrict__ embh,
                                   uint2* __restrict__ c1h) {
    int wid = (blockIdx.x * blockDim.x + threadIdx.x) >> 6;
    int lane = threadIdx.x & 63;
    int grp = lane >> 4, gl = lane & 15;
    int n = wid * 4 + grp;
    bool act = (n < N_NODES);
    int start = 0, end = 0;
    if (act) { start = rowp[n]; end = rowp[n + 1]; }
    float4 acc = gather_node_v4(start, end, gl, srcw, embh);
    if (act) c1h[(size_t)n * 16 + gl] = make_uint2(pack2(acc.x, acc.y), pack2(acc.z, acc.w));
}

// fused 2-hop: one 64-lane wave per target t; 4 groups take j-edges
// round-robin; cross-group shfl_xor reduce; group 0 writes sums[t].
__global__ void twohop_kernel(const int* __restrict__ user, const int* __restrict__ item,
                              const int* __restrict__ rowp, const int2* __restrict__ srcw,
                              const uint2* __restrict__ c1h,
                              const float* __restrict__ user_emb,
                              const float* __restrict__ item_emb,
                              float* __restrict__ sums) {
    int wid = (blockIdx.x * blockDim.x + threadIdx.x) >> 6;
    int lane = threadIdx.x & 63;
    int grp = lane >> 4, gl = lane & 15;
    if (wid >= 2 * BATCH) return;
    int t = wid;
    int n = (t < BATCH) ? user[t] : USER_NUM + item[t - BATCH];
    int s1 = rowp[n], e1 = rowp[n + 1];
    float4 acc = make_float4(0.f, 0.f, 0.f, 0.f);
    for (int jb = s1 + grp; jb < e1; jb += 4) {
        int2 ej = srcw[jb];                       // group-uniform 8B broadcast
        int sj = ej.x;
        float wj = __int_as_float(ej.y);
        float4 f1 = unpack4(c1h[(size_t)sj * 16 + gl]);
        float4 inner = gather_node_v4(rowp[sj], rowp[sj + 1], gl, srcw, c1h);
        acc.x = fmaf(wj, f1.x + inner.x, acc.x);
        acc.y = fmaf(wj, f1.y + inner.y, acc.y);
        acc.z = fmaf(wj, f1.z + inner.z, acc.z);
        acc.w = fmaf(wj, f1.w + inner.w, acc.w);
    }
    for (int m = 16; m < 64; m <<= 1) {
        acc.x += __shfl_xor(acc.x, m, 64);
        acc.y += __shfl_xor(acc.y, m, 64);
        acc.z += __shfl_xor(acc.z, m, 64);
        acc.w += __shfl_xor(acc.w, m, 64);
    }
    if (grp == 0) {
        const float* ebase = (n < USER_NUM) ? user_emb + (size_t)n * HIDDEN
                                            : item_emb + (size_t)(n - USER_NUM) * HIDDEN;
        float4 ev = *(const float4*)(ebase + gl * 4);
        float4 cv = unpack4(c1h[(size_t)n * 16 + gl]);
        float4 o = make_float4(ev.x + cv.x + acc.x, ev.y + cv.y + acc.y,
                               ev.z + cv.z + acc.z, ev.w + cv.w + acc.w);
        *(float4*)(sums + (size_t)t * HIDDEN + gl * 4) = o;
    }
}

// one 64-lane wave per batch element
__global__ void dot_kernel(const float* __restrict__ sums, float* __restrict__ out) {
    int b = blockIdx.x * (blockDim.x >> 6) + (threadIdx.x >> 6);
    int lane = threadIdx.x & 63;
    if (b >= BATCH) return;
    float su = sums[(size_t)b * HIDDEN + lane];
    float si = sums[(size_t)(BATCH + b) * HIDDEN + lane];
    float p = su * si;
    for (int off = 32; off > 0; off >>= 1) p += __shfl_down(p, off, 64);
    if (lane == 0) {
        float g = 0.0625f * p;  // 0.25 per side (all alphas equal)
        out[b] = 1.0f / (1.0f + expf(-g));
    }
}

extern "C" void kernel_launch(void* const* d_in, const int* in_sizes, int n_in,
                              void* d_out, int out_size, void* d_ws, size_t ws_size,
                              hipStream_t stream) {
    const int*   user     = (const int*)d_in[0];
    const int*   item     = (const int*)d_in[1];
    const int*   src      = (const int*)d_in[2];
    const int*   dst      = (const int*)d_in[3];
    const float* ew       = (const float*)d_in[4];
    const float* user_emb = (const float*)d_in[5];
    const float* item_emb = (const float*)d_in[6];
    float* out = (float*)d_out;

    float* sums    = (float*)d_ws;                                // [8192][64]
    uint2* embh    = (uint2*)(sums + (size_t)2 * BATCH * HIDDEN); // [N_NODES][16]
    uint2* c1h     = embh + (size_t)N_NODES * 16;                 // [N_NODES][16]
    int2*  srcw    = (int2*)(c1h + (size_t)N_NODES * 16);         // NNZ + pad
    int2*  binned  = srcw + NNZ + 16;                             // NBUCK*BCAP
    int*   rowp    = (int*)(binned + (size_t)NBUCK * BCAP);       // N_NODES+1
    int*   cursorB = rowp + N_NODES + 1;                          // NBUCK
    int*   H       = cursorB + NBUCK;                             // NBINA*NBUCK

    // ---- pass 1: per-block histograms + emb->fp16 (fused grid) ----
    convcount_kernel<<<NBINA + CONVB, 256, 0, stream>>>(
        dst, H, user_emb, item_emb, (uint4*)embh);

    // ---- pass 2: per-bucket scan of block counts (no global atomics) ----
    bin_scan_kernel<<<NBUCK, 256, 0, stream>>>(H, cursorB);

    // ---- pass 3: deterministic placement ----
    place_kernel<<<NBINA, 256, 0, stream>>>(src, dst, ew, H, binned);

    // ---- bucket-local CSR finalize ----
    binB_kernel<<<NBUCK, 1024, 0, stream>>>(binned, cursorB, rowp, srcw);

    // ---- layer 1: full (16 nodes per 256-thread block) ----
    const int nodesPerBlock = 16;
    const int nGatherBlocks = (N_NODES + nodesPerBlock - 1) / nodesPerBlock;
    spmm_gather_kernel<<<nGatherBlocks, 256, 0, stream>>>(rowp, srcw, embh, c1h);

    // ---- fused 2-hop: one wave per target ----
    twohop_kernel<<<(2 * BATCH * 64) / 256, 256, 0, stream>>>(
        user, item, rowp, srcw, c1h, user_emb, item_emb, sums);

    dot_kernel<<<(BATCH * 64 + 255) / 256, 256, 0, stream>>>(sums, out);
}

// Round 18
// 100.127 us; speedup vs baseline: 1.2641x; 1.0235x over previous
//
#include <hip/hip_runtime.h>
#include <hip/hip_fp16.h>

#define USER_NUM 100000
#define ITEM_NUM 50000
#define N_NODES  150000
#define NNZ      1200000
#define BATCH    4096
#define HIDDEN   64

#define BUCK_SHIFT 10
#define NBUCK 147        // ceil(150000/1024)
#define BCAP  10240      // fixed bucket capacity (mean 8192, sigma ~90)
#define BINA_CHUNK 4096  // edges per block (16 per thread)
#define NBINA ((NNZ + BINA_CHUNK - 1) / BINA_CHUNK)   // 293
#define TOTAL8 (N_NODES * HIDDEN / 8)                  // 1.2M
#define CONVB ((TOTAL8 + 255) / 256)                   // 4688

// ---- fp16 pack/unpack (RNE, exact widen) ----
__device__ __forceinline__ unsigned pack2(float a, float b) {
    __half2 h = __floats2half2_rn(a, b);
    return *(unsigned*)&h;
}
__device__ __forceinline__ float4 unpack4(uint2 u) {
    __half2 h0 = *(__half2*)&u.x;
    __half2 h1 = *(__half2*)&u.y;
    float2 f0 = __half22float2(h0);
    float2 f1 = __half22float2(h1);
    return make_float4(f0.x, f0.y, f1.x, f1.y);
}

// pass 1: per-block bucket histogram -> H (pure counting, 4.8 MB read)
__global__ void count_kernel(const int* __restrict__ dst, int* __restrict__ H) {
    __shared__ int hist[NBUCK];
    const int chunk0 = blockIdx.x * BINA_CHUNK;
    for (int i = threadIdx.x; i < NBUCK; i += 256) hist[i] = 0;
    __syncthreads();
    for (int k = 0; k < BINA_CHUNK / 256; ++k) {
        int e = chunk0 + k * 256 + threadIdx.x;
        if (e < NNZ) atomicAdd(&hist[dst[e] >> BUCK_SHIFT], 1);
    }
    __syncthreads();
    for (int i = threadIdx.x; i < NBUCK; i += 256) H[blockIdx.x * NBUCK + i] = hist[i];
}

// pass 2: one block per bucket; exclusive scan of the 293 block counts,
// written back in place; bucket total -> cursorB[b]
__global__ void bin_scan_kernel(int* __restrict__ H, int* __restrict__ cursorB) {
    __shared__ int lds[256];
    __shared__ int carry;
    const int b = blockIdx.x;
    if (threadIdx.x == 0) carry = 0;
    __syncthreads();
    for (int t0 = 0; t0 < NBINA; t0 += 256) {
        int j = t0 + threadIdx.x;
        int v = (j < NBINA) ? H[j * NBUCK + b] : 0;
        lds[threadIdx.x] = v;
        __syncthreads();
        for (int off = 1; off < 256; off <<= 1) {
            int t = (threadIdx.x >= off) ? lds[threadIdx.x - off] : 0;
            __syncthreads();
            lds[threadIdx.x] += t;
            __syncthreads();
        }
        int excl = lds[threadIdx.x] - v + carry;
        if (j < NBINA) H[j * NBUCK + b] = excl;
        __syncthreads();
        if (threadIdx.x == 255) carry += lds[255];
        __syncthreads();
    }
    if (threadIdx.x == 0) cursorB[b] = carry;
}

// pass 3 (fused): blocks [0,NBINA) deterministic placement (LDS-only rank
// atomics, base from H); blocks [NBINA,...) emb f32 -> packed fp16 table.
// place is 14%-occupancy latency-bound; convert fills the idle CUs.
__global__ void place_conv_kernel(const int* __restrict__ src, const int* __restrict__ dst,
                                  const float* __restrict__ ew,
                                  const int* __restrict__ H, int2* __restrict__ binned,
                                  const float* __restrict__ ue, const float* __restrict__ ie,
                                  uint4* __restrict__ embh) {
    if (blockIdx.x >= NBINA) {
        int idx = (blockIdx.x - NBINA) * blockDim.x + threadIdx.x;
        if (idx >= TOTAL8) return;
        const int usz8 = USER_NUM * HIDDEN / 8;
        const float4* base = (idx < usz8) ? (const float4*)ue + (size_t)idx * 2
                                          : (const float4*)ie + (size_t)(idx - usz8) * 2;
        float4 a = base[0], b = base[1];
        embh[idx] = make_uint4(pack2(a.x, a.y), pack2(a.z, a.w),
                               pack2(b.x, b.y), pack2(b.z, b.w));
        return;
    }
    __shared__ int rank[NBUCK];
    __shared__ int base[NBUCK];
    const int chunk0 = blockIdx.x * BINA_CHUNK;
    for (int i = threadIdx.x; i < NBUCK; i += 256) {
        base[i] = H[blockIdx.x * NBUCK + i];
        rank[i] = 0;
    }
    __syncthreads();
    for (int k = 0; k < BINA_CHUNK / 256; ++k) {
        int e = chunk0 + k * 256 + threadIdx.x;
        if (e < NNZ) {
            int d = dst[e];
            int b = d >> BUCK_SHIFT;
            int r = atomicAdd(&rank[b], 1);
            binned[(size_t)b * BCAP + base[b] + r] =
                make_int2(src[e] | ((d & 1023) << 18), __float_as_int(ew[e]));
        }
    }
}

// pass B: one block per bucket. Inline global-base scan, LDS per-node
// histogram -> block scan -> coalesced rowp write -> LDS-cursor scatter.
__global__ __launch_bounds__(1024) void binB_kernel(const int2* __restrict__ binned,
                                                    const int* __restrict__ cursorB,
                                                    int* __restrict__ rowp,
                                                    int2* __restrict__ srcw) {
    __shared__ int hist[1 << BUCK_SHIFT];
    __shared__ int sb[256];
    __shared__ int wsum[16];
    const int b = blockIdx.x;
    const int tid = threadIdx.x;
    hist[tid] = 0;
    if (tid < 256) sb[tid] = (tid < NBUCK) ? cursorB[tid] : 0;
    __syncthreads();
    for (int off = 1; off < 256; off <<= 1) {
        int t2 = 0;
        if (tid < 256 && tid >= off) t2 = sb[tid - off];
        __syncthreads();
        if (tid < 256) sb[tid] += t2;
        __syncthreads();
    }
    const int bucketBase = (b == 0) ? 0 : sb[b - 1];
    const int cnt = cursorB[b];
    const size_t lo = (size_t)b * BCAP;
    for (int i = tid; i < cnt; i += 1024)
        atomicAdd(&hist[(unsigned)binned[lo + i].x >> 18], 1);
    __syncthreads();
    const int v = hist[tid];
    const int lane = tid & 63, w = tid >> 6;
    int x = v;
    for (int off = 1; off < 64; off <<= 1) {
        int y = __shfl_up(x, off, 64);
        if (lane >= off) x += y;
    }
    if (lane == 63) wsum[w] = x;
    __syncthreads();
    if (tid < 16) {
        int orig = wsum[tid];
        int s = orig;
        for (int off = 1; off < 16; off <<= 1) {
            int y = __shfl_up(s, off, 64);
            if (tid >= off) s += y;
        }
        wsum[tid] = s - orig;
    }
    __syncthreads();
    const int excl = bucketBase + (x - v) + wsum[w];
    const int nodeBase = b << BUCK_SHIFT;
    if (nodeBase + tid < N_NODES) rowp[nodeBase + tid] = excl;
    if (b == 0 && tid == 0) rowp[N_NODES] = NNZ;
    hist[tid] = excl;
    __syncthreads();
    for (int i = tid; i < cnt; i += 1024) {
        int2 p = binned[lo + i];
        int dl = (unsigned)p.x >> 18;
        int pos = atomicAdd(&hist[dl], 1);
        srcw[pos] = make_int2(p.x & 0x3FFFF, p.y);
    }
}

// ---- gather core v4: 16-lane group per node, fp16 rows (128B = uint2/lane),
// coalesced edge load + shfl redistribute, 8 rows in flight, f32 accum ----
__device__ __forceinline__ float4 gather_node_v4(int start, int end, int gl,
                                                 const int2* __restrict__ srcw,
                                                 const uint2* __restrict__ rows) {
    float4 acc = make_float4(0.f, 0.f, 0.f, 0.f);
    for (int base = start; base < end; base += 16) {
        int2 e = make_int2(0, 0);
        if (base + gl < end) e = srcw[base + gl];   // one coalesced 128B load per group
        int m = end - base; if (m > 16) m = 16;
        for (int j0 = 0; j0 < m; j0 += 8) {
            const uint2* bp[8];
            float w[8];
            #pragma unroll
            for (int k = 0; k < 8; ++k) {
                int idx = j0 + k;
                int ss = __shfl(e.x, idx, 16);
                float ww = __int_as_float(__shfl(e.y, idx, 16));
                bool valid = idx < m;
                ss = valid ? ss : 0;
                w[k] = valid ? ww : 0.f;
                bp[k] = rows + (size_t)ss * 16 + gl;
            }
            uint2 v[8];
            #pragma unroll
            for (int k = 0; k < 8; ++k) v[k] = *bp[k];
            #pragma unroll
            for (int k = 0; k < 8; ++k) {
                float4 f = unpack4(v[k]);
                acc.x = fmaf(w[k], f.x, acc.x);
                acc.y = fmaf(w[k], f.y, acc.y);
                acc.z = fmaf(w[k], f.z, acc.z);
                acc.w = fmaf(w[k], f.w, acc.w);
            }
        }
    }
    return acc;
}

// layer 1: all nodes; gathers fp16 emb rows, writes fp16 c1h
__global__ void spmm_gather_kernel(const int* __restrict__ rowp,
                                   const int2* __restrict__ srcw,
                                   const uint2* __restrict__ embh,
                                   uint2* __restrict__ c1h) {
    int wid = (blockIdx.x * blockDim.x + threadIdx.x) >> 6;
    int lane = threadIdx.x & 63;
    int grp = lane >> 4, gl = lane & 15;
    int n = wid * 4 + grp;
    bool act = (n < N_NODES);
    int start = 0, end = 0;
    if (act) { start = rowp[n]; end = rowp[n + 1]; }
    float4 acc = gather_node_v4(start, end, gl, srcw, embh);
    if (act) c1h[(size_t)n * 16 + gl] = make_uint2(pack2(acc.x, acc.y), pack2(acc.z, acc.w));
}

// fused 2-hop: one 64-lane wave per target t; 4 groups take j-edges
// round-robin; cross-group shfl_xor reduce; group 0 writes sums[t].
__global__ void twohop_kernel(const int* __restrict__ user, const int* __restrict__ item,
                              const int* __restrict__ rowp, const int2* __restrict__ srcw,
                              const uint2* __restrict__ c1h,
                              const float* __restrict__ user_emb,
                              const float* __restrict__ item_emb,
                              float* __restrict__ sums) {
    int wid = (blockIdx.x * blockDim.x + threadIdx.x) >> 6;
    int lane = threadIdx.x & 63;
    int grp = lane >> 4, gl = lane & 15;
    if (wid >= 2 * BATCH) return;
    int t = wid;
    int n = (t < BATCH) ? user[t] : USER_NUM + item[t - BATCH];
    int s1 = rowp[n], e1 = rowp[n + 1];
    float4 acc = make_float4(0.f, 0.f, 0.f, 0.f);
    for (int jb = s1 + grp; jb < e1; jb += 4) {
        int2 ej = srcw[jb];                       // group-uniform 8B broadcast
        int sj = ej.x;
        float wj = __int_as_float(ej.y);
        float4 f1 = unpack4(c1h[(size_t)sj * 16 + gl]);
        float4 inner = gather_node_v4(rowp[sj], rowp[sj + 1], gl, srcw, c1h);
        acc.x = fmaf(wj, f1.x + inner.x, acc.x);
        acc.y = fmaf(wj, f1.y + inner.y, acc.y);
        acc.z = fmaf(wj, f1.z + inner.z, acc.z);
        acc.w = fmaf(wj, f1.w + inner.w, acc.w);
    }
    for (int m = 16; m < 64; m <<= 1) {
        acc.x += __shfl_xor(acc.x, m, 64);
        acc.y += __shfl_xor(acc.y, m, 64);
        acc.z += __shfl_xor(acc.z, m, 64);
        acc.w += __shfl_xor(acc.w, m, 64);
    }
    if (grp == 0) {
        const float* ebase = (n < USER_NUM) ? user_emb + (size_t)n * HIDDEN
                                            : item_emb + (size_t)(n - USER_NUM) * HIDDEN;
        float4 ev = *(const float4*)(ebase + gl * 4);
        float4 cv = unpack4(c1h[(size_t)n * 16 + gl]);
        float4 o = make_float4(ev.x + cv.x + acc.x, ev.y + cv.y + acc.y,
                               ev.z + cv.z + acc.z, ev.w + cv.w + acc.w);
        *(float4*)(sums + (size_t)t * HIDDEN + gl * 4) = o;
    }
}

// one 64-lane wave per batch element
__global__ void dot_kernel(const float* __restrict__ sums, float* __restrict__ out) {
    int b = blockIdx.x * (blockDim.x >> 6) + (threadIdx.x >> 6);
    int lane = threadIdx.x & 63;
    if (b >= BATCH) return;
    float su = sums[(size_t)b * HIDDEN + lane];
    float si = sums[(size_t)(BATCH + b) * HIDDEN + lane];
    float p = su * si;
    for (int off = 32; off > 0; off >>= 1) p += __shfl_down(p, off, 64);
    if (lane == 0) {
        float g = 0.0625f * p;  // 0.25 per side (all alphas equal)
        out[b] = 1.0f / (1.0f + expf(-g));
    }
}

extern "C" void kernel_launch(void* const* d_in, const int* in_sizes, int n_in,
                              void* d_out, int out_size, void* d_ws, size_t ws_size,
                              hipStream_t stream) {
    const int*   user     = (const int*)d_in[0];
    const int*   item     = (const int*)d_in[1];
    const int*   src      = (const int*)d_in[2];
    const int*   dst      = (const int*)d_in[3];
    const float* ew       = (const float*)d_in[4];
    const float* user_emb = (const float*)d_in[5];
    const float* item_emb = (const float*)d_in[6];
    float* out = (float*)d_out;

    float* sums    = (float*)d_ws;                                // [8192][64]
    uint2* embh    = (uint2*)(sums + (size_t)2 * BATCH * HIDDEN); // [N_NODES][16]
    uint2* c1h     = embh + (size_t)N_NODES * 16;                 // [N_NODES][16]
    int2*  srcw    = (int2*)(c1h + (size_t)N_NODES * 16);         // NNZ + pad
    int2*  binned  = srcw + NNZ + 16;                             // NBUCK*BCAP
    int*   rowp    = (int*)(binned + (size_t)NBUCK * BCAP);       // N_NODES+1
    int*   cursorB = rowp + N_NODES + 1;                          // NBUCK
    int*   H       = cursorB + NBUCK;                             // NBINA*NBUCK

    // ---- pass 1: per-block histograms only (4.8 MB) ----
    count_kernel<<<NBINA, 256, 0, stream>>>(dst, H);

    // ---- pass 2: per-bucket scan of block counts ----
    bin_scan_kernel<<<NBUCK, 256, 0, stream>>>(H, cursorB);

    // ---- pass 3: placement (14% occ) + emb->fp16 convert fused ----
    place_conv_kernel<<<NBINA + CONVB, 256, 0, stream>>>(
        src, dst, ew, H, binned, user_emb, item_emb, (uint4*)embh);

    // ---- bucket-local CSR finalize ----
    binB_kernel<<<NBUCK, 1024, 0, stream>>>(binned, cursorB, rowp, srcw);

    // ---- layer 1: full (16 nodes per 256-thread block) ----
    const int nodesPerBlock = 16;
    const int nGatherBlocks = (N_NODES + nodesPerBlock - 1) / nodesPerBlock;
    spmm_gather_kernel<<<nGatherBlocks, 256, 0, stream>>>(rowp, srcw, embh, c1h);

    // ---- fused 2-hop: one wave per target ----
    twohop_kernel<<<(2 * BATCH * 64) / 256, 256, 0, stream>>>(
        user, item, rowp, srcw, c1h, user_emb, item_emb, sums);

    dot_kernel<<<(BATCH * 64 + 255) / 256, 256, 0, stream>>>(sums, out);
}